// Round 10
// baseline (182.665 us; speedup 1.0000x reference)
//
#include <hip/hip_runtime.h>

#define NROW 4096
#define DIM  1024
#define TEMP_INV 14.285714285714286f /* 1/0.07 */
#define NBINS 2048
#define HSLOTS 2304  /* 2048 bins + 4-word pad per 32: slot(b) = b + ((b>>5)<<2) */

typedef __attribute__((ext_vector_type(8))) short bf16x8;
typedef __attribute__((ext_vector_type(4))) float f32x4;

__device__ __forceinline__ unsigned f2bf_u(float f) {
  unsigned u = __float_as_uint(f);
  return (u + 0x7FFFu + ((u >> 16) & 1u)) >> 16;  // RNE bf16
}

__device__ __forceinline__ float wave_sum_f(float v) {
#pragma unroll
  for (int off = 32; off > 0; off >>= 1) v += __shfl_down(v, off);
  return v;
}

// ---------------- Kernel 1: L2 normalize rows, emit bf16 ----------------
__global__ __launch_bounds__(256) void normalize_k(const float* __restrict__ X,
                                                   unsigned short* __restrict__ FB) {
  __shared__ float warp_s[4];
  const int row = blockIdx.x;
  const int tid = threadIdx.x;
  const float4* x4 = (const float4*)(X + (size_t)row * DIM);
  float4 v = x4[tid];  // 256 threads * 4 = 1024
  float ss = v.x * v.x + v.y * v.y + v.z * v.z + v.w * v.w;
  ss = wave_sum_f(ss);
  if ((tid & 63) == 0) warp_s[tid >> 6] = ss;
  __syncthreads();
  float total = warp_s[0] + warp_s[1] + warp_s[2] + warp_s[3];
  float inv = 1.0f / fmaxf(sqrtf(total), 1e-12f);
  ushort4 o;
  o.x = (unsigned short)f2bf_u(v.x * inv);
  o.y = (unsigned short)f2bf_u(v.y * inv);
  o.z = (unsigned short)f2bf_u(v.z * inv);
  o.w = (unsigned short)f2bf_u(v.w * inv);
  ((ushort4*)(FB + (size_t)row * DIM))[tid] = o;
}

// ---------------- Kernel 2: sim = (FB @ FB^T) * (1/T), f32 out ----------------
// 128x128 tile, BK=32, 4 waves (64x64 each), 16x16x32 bf16 MFMA.
// T4 counted-vmcnt 3-buffer pipeline (prefetch distance 2), 48 KB LDS ->
// 3 blocks/CU (12 waves). body(t): vmcnt(4) [stage(t) landed; stage(t+1)'s 4
// loads STAY IN FLIGHT across the barrier] -> raw s_barrier -> stage(t+2) ->
// compute(t). Race proof: stage(t+2) overwrites buf[(t-1)%3]; all waves passed
// barrier(t) => finished compute(t-1). Per-wave vmcnt before barrier => all
// waves' stage(t) LDS writes landed before any wave exits the barrier.
// LDS layout (row-pairing so the 8-unit XOR swizzle survives BK=32):
//   LDS row R (128 B = 8x16B units): units 0-3 = real row R, k-units 0-3;
//   units 4-7 = real row R+64, k-units 0-3; stored at unit' = unit ^ (R&7)
//   via inverse-swizzled GLOBAL source (linear LDS dest for global_load_lds).
// ds_read: addr = (row&63)*64sh + (((k/8) + 4*(row>>6)) ^ (row&7))*8sh -> 2-way
// bank access (free). T1 XCD swizzle kept (1024 blocks % 8 == 0).
__global__ __launch_bounds__(256) void gemm_sim(const unsigned short* __restrict__ FB,
                                                float* __restrict__ C) {
  __shared__ unsigned short Ls[3][2][64 * 64] __attribute__((aligned(16)));  // 3 x 16 KB
  const int tid  = threadIdx.x;
  const int wave = tid >> 6;
  const int lane = tid & 63;
  const int wr = wave >> 1;  // wave row 0..1
  const int wc = wave & 1;   // wave col 0..1

  const int bid = blockIdx.x;
  const int swz = (bid & 7) * 128 + (bid >> 3);
  const int brow = (swz >> 5) * 128;
  const int bcol = (swz & 31) * 128;

  f32x4 acc[4][4];
#pragma unroll
  for (int m = 0; m < 4; ++m)
#pragma unroll
    for (int n = 0; n < 4; ++n) acc[m][n] = (f32x4){0.f, 0.f, 0.f, 0.f};

  // ---- staging lane geometry ----
  // instr i in {0,1}: LDS rows i*32 + wave*8 + lane/8, landing unit lane%8.
  // source must hold the INVERSE-swizzled element: u = (lane%8) ^ (lane/8);
  // real row = i*32 + R0 + (u>=4)*64, real k-unit = u&3.
  const int R0  = wave * 8 + (lane >> 3);
  const int u   = (lane & 7) ^ (lane >> 3);
  const int scu = (u & 3) * 8;              // source col (shorts)
  const int rhi = (u >> 2) * 64;            // +64 rows if u >= 4
  const unsigned short* gA0 = FB + (size_t)(brow + R0 + rhi) * DIM + scu;
  const unsigned short* gA1 = FB + (size_t)(brow + 32 + R0 + rhi) * DIM + scu;
  const unsigned short* gB0 = FB + (size_t)(bcol + R0 + rhi) * DIM + scu;
  const unsigned short* gB1 = FB + (size_t)(bcol + 32 + R0 + rhi) * DIM + scu;
  const int ld0 = wave * 512;               // LDS base (shorts); instr1 adds 2048

#define STAGE(LA, LB, k0) do {                                                              \
  __builtin_amdgcn_global_load_lds((const __attribute__((address_space(1))) unsigned int*)(gA0 + (k0)), \
      (__attribute__((address_space(3))) unsigned int*)((LA) + ld0), 16, 0, 0);             \
  __builtin_amdgcn_global_load_lds((const __attribute__((address_space(1))) unsigned int*)(gA1 + (k0)), \
      (__attribute__((address_space(3))) unsigned int*)((LA) + 2048 + ld0), 16, 0, 0);      \
  __builtin_amdgcn_global_load_lds((const __attribute__((address_space(1))) unsigned int*)(gB0 + (k0)), \
      (__attribute__((address_space(3))) unsigned int*)((LB) + ld0), 16, 0, 0);             \
  __builtin_amdgcn_global_load_lds((const __attribute__((address_space(1))) unsigned int*)(gB1 + (k0)), \
      (__attribute__((address_space(3))) unsigned int*)((LB) + 2048 + ld0), 16, 0, 0);      \
} while (0)

  // ---- ds_read lane geometry ----
  const int fr  = lane & 15;                 // fragment row within 16
  const int uA  = (lane >> 4) + wr * 4;      // unswizzled unit for A reads
  const int uB  = (lane >> 4) + wc * 4;      // for B reads
  const int swA = fr * 64 + ((uA ^ (fr & 7)) << 3);  // shorts; + m*1024
  const int swB = fr * 64 + ((uB ^ (fr & 7)) << 3);  // shorts; + n*1024

  unsigned short* A0 = &Ls[0][0][0]; unsigned short* B0 = &Ls[0][1][0];
  unsigned short* A1 = &Ls[1][0][0]; unsigned short* B1 = &Ls[1][1][0];
  unsigned short* A2 = &Ls[2][0][0]; unsigned short* B2 = &Ls[2][1][0];
  unsigned short *Acur = A0, *Bcur = B0, *Anxt = A1, *Bnxt = B1, *Afut = A2, *Bfut = B2;

  STAGE(Acur, Bcur, 0);
  STAGE(Anxt, Bnxt, 32);

  const int nt = DIM / 32;  // 32
  for (int t = 0; t < nt; ++t) {
    if (t < nt - 1) asm volatile("s_waitcnt vmcnt(4)" ::: "memory");
    else            asm volatile("s_waitcnt vmcnt(0)" ::: "memory");
    __builtin_amdgcn_s_barrier();

    if (t + 2 < nt) STAGE(Afut, Bfut, (t + 2) * 32);

    bf16x8 af[4], bg[4];
#pragma unroll
    for (int m = 0; m < 4; ++m) af[m] = *(const bf16x8*)&Acur[swA + m * 1024];
#pragma unroll
    for (int n = 0; n < 4; ++n) bg[n] = *(const bf16x8*)&Bcur[swB + n * 1024];
#pragma unroll
    for (int m = 0; m < 4; ++m)
#pragma unroll
      for (int n = 0; n < 4; ++n)
        acc[m][n] = __builtin_amdgcn_mfma_f32_16x16x32_bf16(af[m], bg[n], acc[m][n], 0, 0, 0);

    unsigned short* tA = Acur; Acur = Anxt; Anxt = Afut; Afut = tA;
    unsigned short* tB = Bcur; Bcur = Bnxt; Bnxt = Bfut; Bfut = tB;
  }
#undef STAGE

  const int rsub = (lane >> 4) * 4;
#pragma unroll
  for (int m = 0; m < 4; ++m)
#pragma unroll
    for (int n = 0; n < 4; ++n) {
      const int r0 = brow + wr * 64 + m * 16 + rsub;
      const int c  = bcol + wc * 64 + n * 16 + fr;
#pragma unroll
      for (int i = 0; i < 4; ++i)
        C[(size_t)(r0 + i) * NROW + c] = acc[m][n][i] * TEMP_INV;
    }
}

// ---------------- Kernel 3: per-row hard mining + loss (fused reduce) --------
// TWO waves per row, 4 rows per 512-thread block (occupancy cap 32 waves/CU).
// 32 elems/lane halves the serial VALU chain vs 1-wave/row. 4 __syncthreads.
// Fixed-range histogram select (|sim| <= 14.41 < 16 proven -> no clamp).
__global__ __launch_bounds__(512) void row_loss_k(const float* __restrict__ S,
                                                  const int* __restrict__ labels,
                                                  float* __restrict__ out) {
  __shared__ unsigned hist[4][HSLOTS] __attribute__((aligned(16)));  // 36.9 KB
  __shared__ int nnegs[4];
  __shared__ int bsels[4];
  __shared__ float accs[4][4];  // negexp, possum, selfv, pc
  const int tid  = threadIdx.x;
  const int wave = tid >> 6;
  const int lane = tid & 63;
  const int rl   = wave >> 1;   // row within block 0..3
  const int half = wave & 1;    // which half of the row this wave owns
  const int row  = blockIdx.x * 4 + rl;
  const int my   = labels[row];
  unsigned* H = hist[rl];

  // zero hist (2304 uint4 over 512 threads) + small arrays
  for (int i = tid; i < (4 * HSLOTS) / 4; i += 512)
    ((uint4*)hist)[i] = (uint4){0u, 0u, 0u, 0u};
  if (tid < 4) { nnegs[tid] = 0; bsels[tid] = NBINS; }
  if (tid < 16) accs[tid >> 2][tid & 3] = 0.f;

  // masks: float4 index i0 + e*64, e in [0,8); column j = idx*4 + c
  const float4* rp = (const float4*)(S + (size_t)row * NROW);
  const int4*   lp = (const int4*)labels;
  const int i0 = half * 512 + lane;
  unsigned negm = 0u, posm = 0u;
#pragma unroll
  for (int e = 0; e < 8; ++e) {
    int4 lb = lp[i0 + e * 64];
    const int j0 = (i0 + e * 64) * 4;
    if (lb.x != my) negm |= 1u << (e * 4 + 0); else if (j0 + 0 != row) posm |= 1u << (e * 4 + 0);
    if (lb.y != my) negm |= 1u << (e * 4 + 1); else if (j0 + 1 != row) posm |= 1u << (e * 4 + 1);
    if (lb.z != my) negm |= 1u << (e * 4 + 2); else if (j0 + 2 != row) posm |= 1u << (e * 4 + 2);
    if (lb.w != my) negm |= 1u << (e * 4 + 3); else if (j0 + 3 != row) posm |= 1u << (e * 4 + 3);
  }
  int pn = __popc(negm);
#pragma unroll
  for (int off = 32; off > 0; off >>= 1) pn += __shfl_xor(pn, off);
  if (lane == 0) atomicAdd(&nnegs[rl], pn);
  __syncthreads();  // zeros + nnegs visible

  // histogram fill (no clamp: bins provably in [101, 1946])
#pragma unroll
  for (int e = 0; e < 8; ++e) {
    float4 v4 = rp[i0 + e * 64];
#pragma unroll
    for (int c = 0; c < 4; ++c) {
      if ((negm >> (e * 4 + c)) & 1u) {
        float v = ((const float*)&v4)[c];
        int b = (int)((v + 16.0f) * 64.0f);
        atomicAdd(&H[b + ((b >> 5) << 2)], 1u);
      }
    }
  }
  __syncthreads();  // fill complete across both waves

  if (half == 0) {
    int k = nnegs[rl] >> 1;  // floor(count*0.5)
    if (k < 1) k = 1;
    // suffix scan: lane owns bins [lane*32, lane*32+32) at slots lane*36+0..31
    int ts = 0;
#pragma unroll
    for (int z = 0; z < 8; ++z) {
      uint4 h = *(const uint4*)&H[lane * 36 + z * 4];
      ts += (int)(h.x + h.y + h.z + h.w);
    }
    int sfx = ts;
#pragma unroll
    for (int off = 1; off < 64; off <<= 1) {
      int t = __shfl_down(sfx, off);
      sfx += (lane + off < 64) ? t : 0;
    }
    int snext = __shfl_down(sfx, 1);
    if (lane == 63) snext = 0;
    const bool iscross = (sfx >= k) && (snext < k);
    int B = -1;
    int run = snext;
#pragma unroll
    for (int z = 7; z >= 0; --z) {
      uint4 h = *(const uint4*)&H[lane * 36 + z * 4];
      run += (int)h.w; if (B < 0 && run >= k) B = z * 4 + 3;
      run += (int)h.z; if (B < 0 && run >= k) B = z * 4 + 2;
      run += (int)h.y; if (B < 0 && run >= k) B = z * 4 + 1;
      run += (int)h.x; if (B < 0 && run >= k) B = z * 4 + 0;
    }
    B = iscross ? (lane * 32 + B) : -1;
    unsigned long long mB = __ballot(B >= 0);
    int Bsel = NBINS;
    if (mB != 0ull) {
      int src = __ffsll(mB) - 1;
      Bsel = __shfl(B, src);
    }
    if (lane == 0) bsels[rl] = Bsel;
  }
  __syncthreads();
  const int Bsel = bsels[rl];

  // fused final pass (both waves; bin recomputed with the identical expression
  // used in the fill -> perfectly consistent selection)
  float negexp = 0.f, possum = 0.f, selfv = 0.f;
  int pc = 0;
#pragma unroll
  for (int e = 0; e < 8; ++e) {
    float4 v4 = rp[i0 + e * 64];
#pragma unroll
    for (int c = 0; c < 4; ++c) {
      const int bit = e * 4 + c;
      const int j = (i0 + e * 64) * 4 + c;
      float v = ((const float*)&v4)[c];
      int b = (int)((v + 16.0f) * 64.0f);
      bool sel = ((negm >> bit) & 1u) && (b >= Bsel);
      negexp += __expf(sel ? v : -1e30f);  // exp(-1e30) -> 0
      if ((posm >> bit) & 1u) { possum += v; pc++; }
      if (j == row) selfv = v;
    }
  }
#pragma unroll
  for (int off = 32; off > 0; off >>= 1) {
    negexp += __shfl_xor(negexp, off);
    possum += __shfl_xor(possum, off);
    selfv  += __shfl_xor(selfv, off);
    pc     += __shfl_xor(pc, off);
  }
  if (lane == 0) {
    atomicAdd(&accs[rl][0], negexp);
    atomicAdd(&accs[rl][1], possum);
    atomicAdd(&accs[rl][2], selfv);
    atomicAdd(&accs[rl][3], (float)pc);
  }
  __syncthreads();
  if (half == 0 && lane == 0) {
    float ne = accs[rl][0], ps = accs[rl][1], sv = accs[rl][2], pcf = accs[rl][3];
    float denom = ne + expf(sv) + 1e-10f;
    float logd = logf(denom);
    float mlpp = (ps - pcf * logd) / (pcf + 1e-10f);
    atomicAdd(out, -mlpp * (1.0f / (float)NROW));
  }
}

// ---------------- launcher ----------------
extern "C" void kernel_launch(void* const* d_in, const int* in_sizes, int n_in,
                              void* d_out, int out_size, void* d_ws, size_t ws_size,
                              hipStream_t stream) {
  const float* X    = (const float*)d_in[0];
  const int* labels = (const int*)d_in[1];
  float* out        = (float*)d_out;

  unsigned short* FB = (unsigned short*)d_ws;                       // 8 MB bf16
  float* S = (float*)((char*)d_ws + (size_t)NROW * DIM * 2);        // 64 MB f32

  hipMemsetAsync(out, 0, sizeof(float), stream);
  normalize_k<<<NROW, 256, 0, stream>>>(X, FB);
  gemm_sim<<<1024, 256, 0, stream>>>(FB, S);
  row_loss_k<<<NROW / 4, 512, 0, stream>>>(S, labels, out);
}